// Round 2
// baseline (50.473 us; speedup 1.0000x reference)
//
#include <hip/hip_runtime.h>
#include <stdint.h>

#define BB 1024   // batches
#define TT 1024   // input bits per batch
#define NN 2048   // neurons
#define NBITS 16  // address bits
#define MM 65536  // table entries per neuron
#define BW (BB/64) // 16 uint64 words per t (batch-dimension bit-packing)

// Kernel 1: transpose+pack input_bits (B x T int32) into bitsT[t][w] where
// bit j of bitsT[t][w] = (input_bits[w*64+j][t] != 0).
// grid: (T/64, B/64), block: 256 threads (4 waves, each wave covers 16 t's).
__global__ void pack_transpose_kernel(const int* __restrict__ in,
                                      unsigned long long* __restrict__ bitsT) {
    const int lane = threadIdx.x & 63;
    const int wave = threadIdx.x >> 6;
    const int w  = blockIdx.y;                 // batch word index
    const int t0 = blockIdx.x * 64 + wave * 16;
    const int b  = w * 64 + lane;
    const int* row = in + (size_t)b * TT;
    #pragma unroll
    for (int i = 0; i < 16; ++i) {
        const int t = t0 + i;
        const int v = row[t];                  // each lane streams 64B of its row
        unsigned long long m = __ballot(v != 0);
        if (lane == 0) bitsT[(size_t)t * BW + w] = m;
    }
}

// Kernel 2: for each (b, n): addr = sum_k bit(b, conn[n][k]) << (15-k);
// out[b][n] = (table[n][addr] == 1.0f) as int32 0/1.
// grid: (N/16, B/256), block 256. Thread (tn = tid&15, s = tid>>4) handles
// neuron n = bx*16+tn, batches b0..b0+15 with b0 = by*256 + s*16.
__global__ void lookup_kernel(const int* __restrict__ conn,
                              const float* __restrict__ table,
                              const unsigned long long* __restrict__ bitsT,
                              int* __restrict__ out) {
    const int tn = threadIdx.x & 15;
    const int s  = threadIdx.x >> 4;
    const int n  = blockIdx.x * 16 + tn;
    const int b0 = blockIdx.y * 256 + s * 16;

    int tk[NBITS];
    #pragma unroll
    for (int k = 0; k < NBITS; ++k) tk[k] = conn[n * NBITS + k];

    unsigned int hw[NBITS];
    {
        const int w  = b0 >> 6;
        const int jb = b0 & 63;
        #pragma unroll
        for (int k = 0; k < NBITS; ++k) {
            unsigned long long word = bitsT[(size_t)tk[k] * BW + w];
            hw[k] = (unsigned int)(word >> jb) & 0xFFFFu;   // bits for b0..b0+15
        }
    }

    const float* trow = table + (size_t)n * MM;
    #pragma unroll
    for (int j = 0; j < 16; ++j) {
        unsigned int addr = 0;
        #pragma unroll
        for (int k = 0; k < NBITS; ++k) {
            addr |= ((hw[k] >> j) & 1u) << (NBITS - 1 - k);
        }
        const float v = trow[addr];            // random 4B gather within 256KB row
        out[(size_t)(b0 + j) * NN + n] = (v == 1.0f) ? 1 : 0;
    }
}

extern "C" void kernel_launch(void* const* d_in, const int* in_sizes, int n_in,
                              void* d_out, int out_size, void* d_ws, size_t ws_size,
                              hipStream_t stream) {
    const int*   in_bits = (const int*)d_in[0];    // (B, T) int32
    const int*   conn    = (const int*)d_in[1];    // (N, NB) int32
    const float* table   = (const float*)d_in[2];  // (N, M) float32
    int* out = (int*)d_out;                        // (B, N) bool -> int32 0/1

    unsigned long long* bitsT = (unsigned long long*)d_ws; // 128 KB needed

    dim3 g1(TT / 64, BB / 64);
    pack_transpose_kernel<<<g1, 256, 0, stream>>>(in_bits, bitsT);

    dim3 g2(NN / 16, BB / 256);
    lookup_kernel<<<g2, 256, 0, stream>>>(conn, table, bitsT, out);
}